// Round 3
// baseline (337.402 us; speedup 1.0000x reference)
//
#include <hip/hip_runtime.h>

// Problem constants (match reference setup_inputs)
#define BB 32
#define TT 1024
#define NN 512
#define CC 3
#define PS 2
#define NBLK (TT / PS)                 // 512 patch blocks per batch
#define ROW_F4 (NN * CC / 4)           // 384 float4 per (b,t) row
#define PATCH_F4 (PS * ROW_F4)         // 768 float4 per patch block (12 KB)

// Native vector type: __builtin_nontemporal_* requires a clang vector, not
// HIP's float4 class.
typedef float vf4 __attribute__((ext_vector_type(4)));

// One workgroup per (b, j) patch block: PS=2 contiguous rows = 768 float4.
// 256 threads x 3 fully-utilized iterations. One perm load per block; the
// permuted/identity branch is block-uniform (no divergence).
//
// Channel-0 gather: flat float offset within the patch is 4i+k; row length
// 1536 = 0 mod 3, so channel = (4i+k) % 3 = (i+k) % 3. Component comes from
// the permuted source block iff its channel is 0.
__global__ __launch_bounds__(256) void patchperm_kernel(
    const vf4* __restrict__ x,
    const int* __restrict__ perm,
    vf4* __restrict__ out) {
  const int g = blockIdx.x;            // patch index in [0, B*NB)
  const int b = g >> 9;                // NB == 512
  const int j = g & (NBLK - 1);
  const int jp = perm[g];              // perm is (B, NB) flat == g order

  const size_t base = (size_t)g * PATCH_F4;
  const vf4* __restrict__ cur = x + base;
  vf4* __restrict__ o = out + base;

  if (jp == j) {
    // Identity block (~76% of blocks): straight 12 KB vectorized copy.
#pragma unroll
    for (int k = 0; k < 3; ++k) {
      const int i = threadIdx.x + (k << 8);
      __builtin_nontemporal_store(cur[i], &o[i]);
    }
  } else {
    const vf4* __restrict__ src =
        x + ((size_t)(b * NBLK + jp)) * PATCH_F4;
#pragma unroll
    for (int k = 0; k < 3; ++k) {
      const int i = threadIdx.x + (k << 8);
      const vf4 a = cur[i];
      const vf4 s = src[i];
      const int m = i % 3;
      vf4 w;
      w.x = (m == 0) ? s.x : a.x;  // channel (i+0)%3
      w.y = (m == 2) ? s.y : a.y;  // channel (i+1)%3
      w.z = (m == 1) ? s.z : a.z;  // channel (i+2)%3
      w.w = (m == 0) ? s.w : a.w;  // channel (i+3)%3
      __builtin_nontemporal_store(w, &o[i]);
    }
  }
}

extern "C" void kernel_launch(void* const* d_in, const int* in_sizes, int n_in,
                              void* d_out, int out_size, void* d_ws, size_t ws_size,
                              hipStream_t stream) {
  const vf4* x = (const vf4*)d_in[0];
  const int* perm = (const int*)d_in[1];
  vf4* out = (vf4*)d_out;
  patchperm_kernel<<<BB * NBLK, 256, 0, stream>>>(x, perm, out);
}